// Round 5
// baseline (46622.800 us; speedup 1.0000x reference)
//
#include <hip/hip_runtime.h>
#include <cstdint>
#include <cstddef>

// ---------------------------------------------------------------------------
// Problem constants
// ---------------------------------------------------------------------------
#define NB   32          // batch
#define NT   1000        // time steps
#define NF   513         // features
#define NH   256         // hidden
#define NG   768         // 3*NH gate rows
#define NM   (NB*NT)     // 32000 GEMM rows

#define XP_ELEMS  ((size_t)NM * NG)       // 24,576,000
#define H_ELEMS   ((size_t)NM * NH)       //  8,192,000
#define WPK_ELEMS ((size_t)NG * NH / 2)   //  98,304 (f16x2 words)
#define CB_ELEMS  ((size_t)NG)            //  768 combined-bias floats
#define OUT_HALF  ((size_t)NM * NF)       // 16,416,000

typedef _Float16 f16x2 __attribute__((ext_vector_type(2)));

static __device__ __forceinline__ f16x2 as_f16x2(float x) {
    return __builtin_bit_cast(f16x2, x);
}
static __device__ __forceinline__ f16x2 as_f16x2u(unsigned x) {
    return __builtin_bit_cast(f16x2, x);
}

#if __has_builtin(__builtin_amdgcn_fdot2)
static __device__ __forceinline__ float fdot2(f16x2 h, f16x2 w, float acc) {
    return __builtin_amdgcn_fdot2(h, w, acc, false);
}
#else
static __device__ __forceinline__ float fdot2(f16x2 h, f16x2 w, float acc) {
    return acc + (float)h.x * (float)w.x + (float)h.y * (float)w.y;
}
#endif

// In-VALU butterfly reduce across 8 consecutive lanes (no LDS, no barrier).
// Steps: xor1 (quad_perm [1,0,3,2]), xor2 (quad_perm [2,3,0,1]),
// cross-quad via row_half_mirror (valid because after the first two steps
// every lane of a quad holds the quad sum).
template<int CTRL>
static __device__ __forceinline__ float dpp_add(float x) {
    int t = __builtin_amdgcn_update_dpp(0, __builtin_bit_cast(int, x),
                                        CTRL, 0xF, 0xF, true);
    return x + __builtin_bit_cast(float, t);
}
static __device__ __forceinline__ float red8(float x) {
    x = dpp_add<0xB1>(x);    // quad_perm [1,0,3,2]  : xor 1
    x = dpp_add<0x4E>(x);    // quad_perm [2,3,0,1]  : xor 2
    x = dpp_add<0x141>(x);   // row_half_mirror      : cross-quad
    return x;
}

// ---------------------------------------------------------------------------
// Generic tiled fp32 GEMM:  C[M,N] = A[M,K] @ W[N,K]^T + bias[N]
// CONCAT=true: A is x [32][2][1000][513]; row r=(b*1000+t), feature k is
// concat(x[b,0,t,:], x[b,1,t,:]).
// ---------------------------------------------------------------------------
#define GEMM_BM 128
#define GEMM_BN 64
#define GEMM_BK 16

template<bool CONCAT>
__global__ __launch_bounds__(256) void gemm_bias_kernel(
    const float* __restrict__ A, const float* __restrict__ W,
    const float* __restrict__ bias, float* __restrict__ C,
    int M, int N, int K)
{
    __shared__ float As[GEMM_BK][GEMM_BM];   // k-major
    __shared__ float Bs[GEMM_BK][GEMM_BN];
    const int tid = threadIdx.x;
    const int bm = blockIdx.x * GEMM_BM;
    const int bn = blockIdx.y * GEMM_BN;
    const int mt = tid >> 4;      // 0..15
    const int nt = tid & 15;      // 0..15
    const int m0 = mt * 8;
    const int n0 = nt * 4;

    float acc[8][4];
    #pragma unroll
    for (int i = 0; i < 8; ++i)
        #pragma unroll
        for (int j = 0; j < 4; ++j) acc[i][j] = 0.f;

    const bool kvec = ((K & 3) == 0);   // float4 alignment of row starts

    for (int k0 = 0; k0 < K; k0 += GEMM_BK) {
        // ---- stage A tile (128 rows x 16 k) : 512 quads, 2 per thread ----
        #pragma unroll
        for (int i = 0; i < 2; ++i) {
            int qid = tid * 2 + i;
            int m   = qid >> 2;
            int kq  = (qid & 3) << 2;
            int gm  = bm + m;
            int gk  = k0 + kq;
            float v0 = 0.f, v1 = 0.f, v2 = 0.f, v3 = 0.f;
            if (gm < M) {
                if (!CONCAT) {
                    if (kvec && gk + 4 <= K) {
                        float4 v = *(const float4*)(A + (size_t)gm * K + gk);
                        v0 = v.x; v1 = v.y; v2 = v.z; v3 = v.w;
                    } else {
                        if (gk + 0 < K) v0 = A[(size_t)gm * K + gk + 0];
                        if (gk + 1 < K) v1 = A[(size_t)gm * K + gk + 1];
                        if (gk + 2 < K) v2 = A[(size_t)gm * K + gk + 2];
                        if (gk + 3 < K) v3 = A[(size_t)gm * K + gk + 3];
                    }
                } else {
                    int b = gm / NT;
                    int t = gm - b * NT;
                    float tmp[4];
                    #pragma unroll
                    for (int u = 0; u < 4; ++u) {
                        int f = gk + u;
                        float val = 0.f;
                        if (f < K) {
                            int ch = (f >= NF) ? 1 : 0;
                            int ff = f - ch * NF;
                            val = A[(((size_t)(b * 2 + ch)) * NT + t) * NF + ff];
                        }
                        tmp[u] = val;
                    }
                    v0 = tmp[0]; v1 = tmp[1]; v2 = tmp[2]; v3 = tmp[3];
                }
            }
            As[kq + 0][m] = v0; As[kq + 1][m] = v1;
            As[kq + 2][m] = v2; As[kq + 3][m] = v3;
        }
        // ---- stage B tile (64 n-rows x 16 k) : 256 quads, 1 per thread ----
        {
            int n  = tid >> 2;
            int kq = (tid & 3) << 2;
            int gn = bn + n;
            int gk = k0 + kq;
            float v0 = 0.f, v1 = 0.f, v2 = 0.f, v3 = 0.f;
            if (gn < N) {
                if (kvec && gk + 4 <= K) {
                    float4 v = *(const float4*)(W + (size_t)gn * K + gk);
                    v0 = v.x; v1 = v.y; v2 = v.z; v3 = v.w;
                } else {
                    if (gk + 0 < K) v0 = W[(size_t)gn * K + gk + 0];
                    if (gk + 1 < K) v1 = W[(size_t)gn * K + gk + 1];
                    if (gk + 2 < K) v2 = W[(size_t)gn * K + gk + 2];
                    if (gk + 3 < K) v3 = W[(size_t)gn * K + gk + 3];
                }
            }
            Bs[kq + 0][n] = v0; Bs[kq + 1][n] = v1;
            Bs[kq + 2][n] = v2; Bs[kq + 3][n] = v3;
        }
        __syncthreads();
        // ---- micro-kernel ----
        #pragma unroll
        for (int k = 0; k < GEMM_BK; ++k) {
            float a[8], bb[4];
            *(float4*)&a[0] = *(const float4*)&As[k][m0];
            *(float4*)&a[4] = *(const float4*)&As[k][m0 + 4];
            *(float4*)&bb[0] = *(const float4*)&Bs[k][n0];
            #pragma unroll
            for (int i = 0; i < 8; ++i)
                #pragma unroll
                for (int j = 0; j < 4; ++j)
                    acc[i][j] = fmaf(a[i], bb[j], acc[i][j]);
        }
        __syncthreads();
    }
    // ---- epilogue ----
    #pragma unroll
    for (int i = 0; i < 8; ++i) {
        int gm = bm + m0 + i;
        if (gm >= M) continue;
        #pragma unroll
        for (int j = 0; j < 4; ++j) {
            int gn = bn + n0 + j;
            if (gn < N) C[(size_t)gm * N + gn] = acc[i][j] + bias[gn];
        }
    }
}

// ---------------------------------------------------------------------------
// Pack whh [768][256] fp32 -> f16x2 in the EXACT per-thread order the
// recurrence kernel loads:  wq4[(j*6 + r)*1024 + tid]   (uint4 granules)
// where tid = v*8+q, r indexes the thread's 6 rows
//   rows = {v, 256+v, 512+v, 128+v, 384+v, 640+v}
// and the uint4 covers k2 = 16q + 4j .. +3  (k2 = h-pair index).
// Prologue loads become perfectly coalesced (consecutive tid -> consecutive
// 16B), and it is a one-time 393KB read per workgroup.
// ---------------------------------------------------------------------------
__global__ __launch_bounds__(256) void pack_whh_f16(
    const float* __restrict__ whh, unsigned* __restrict__ wpk)
{
    int idx = blockIdx.x * 256 + threadIdx.x;   // 0..24575, one uint4 each
    int t   = idx & 1023;
    int jr  = idx >> 10;          // 0..23
    int j   = jr / 6;
    int r   = jr - j * 6;
    int v   = t >> 3;
    int q   = t & 7;
    int row = (r < 3) ? (r * 256 + v) : ((r - 3) * 256 + 128 + v);
    int k2b = 16 * q + 4 * j;
    unsigned o[4];
    #pragma unroll
    for (int m = 0; m < 4; ++m) {
        f16x2 w;
        w.x = (_Float16)whh[row * NH + 2 * (k2b + m)];
        w.y = (_Float16)whh[row * NH + 2 * (k2b + m) + 1];
        o[m] = __builtin_bit_cast(unsigned, w);
    }
    ((uint4*)wpk)[idx] = make_uint4(o[0], o[1], o[2], o[3]);
}

// cb[g] = bih[g] + bhh[g] for r/z rows (g<512), bih[g] for n rows.
// (bhh_n must stay separate: n = tanh(xn + r*(Whn.h + bhh_n)).)
// Folding bhh_{r,z} into the xproj GEMM bias saves 4 loop-carried VGPRs
// in the recurrence kernel.
__global__ __launch_bounds__(256) void combine_bias(
    const float* __restrict__ bih, const float* __restrict__ bhh,
    float* __restrict__ cb)
{
    int g = blockIdx.x * 256 + threadIdx.x;   // 0..767
    cb[g] = bih[g] + (g < 2 * NH ? bhh[g] : 0.f);
}

// ---------------------------------------------------------------------------
// GRU recurrence — 1024 threads, 8-way k-split, 6 rows/thread, DPP reduce.
//
// Resource model (why this shape):
//   LDS h-delivery per step  = 768*256*2B / rows_per_thread. rho=6 -> 64KB
//     -> ~500-770 cyc (vs 128KB/1024+ cyc for the old 512-thread layout,
//        and 384KB/3072 cyc for the round-1 row-split which measured
//        exactly its floor, 3087).
//   Weight words per thread  = 768*256/(2*#threads). 1024 thr -> 96 words
//     -> fits the 128-VGPR budget of a 16-wave workgroup, so the compiler
//        has no reason to AGPR-shuffle or L2-re-stream them (the 512-thread
//        192-word variants were stuck at VGPR=116 / 2880 cyc/step for
//        three rounds regardless of source-level pinning tricks).
//
// Thread tid = v*8 + q (v=0..127, q=0..7): owns gate rows
//   {v, 256+v, 512+v} (unit v) and {128+v, 384+v, 640+v} (unit v+128)
// over k in [32q, 32q+32). Partial sums are reduced across the 8 q-lanes
// with a 3-step DPP butterfly (pure VALU, no LDS, no barrier); lane q=0
// then does the gate math for both units. One h f16 buffer in LDS; chunk
// index rotated by (i+q)&3 to turn a 4-way bank conflict into a free 2-way.
// Two parameter sets so real/imag GRUs run concurrently in one launch.
// ---------------------------------------------------------------------------
__global__ __launch_bounds__(1024) void gru_rec_kernel(
    const float* __restrict__ xpA, const unsigned* __restrict__ wpkA,
    const float* __restrict__ bhhA, float* __restrict__ outA,
    const float* __restrict__ xpB, const unsigned* __restrict__ wpkB,
    const float* __restrict__ bhhB, float* __restrict__ outB,
    int nBatch)
{
    const int wg = blockIdx.x;
    const float* xp;  const unsigned* wpk;  const float* bhh;  float* out;  int b;
    if (wg < nBatch) { xp = xpA; wpk = wpkA; bhh = bhhA; out = outA; b = wg; }
    else             { xp = xpB; wpk = wpkB; bhh = bhhB; out = outB; b = wg - nBatch; }

    const int tid = threadIdx.x;       // 0..1023
    const int v   = tid >> 3;          // 0..127
    const int q   = tid & 7;           // k-octant

    // ---- load this thread's 24 weight quads (coalesced, once) ----
    uint4 w[6][4];
    {
        const uint4* wq4 = (const uint4*)wpk;
        #pragma unroll
        for (int j = 0; j < 4; ++j)
            #pragma unroll
            for (int r = 0; r < 6; ++r)
                w[r][j] = wq4[(size_t)(j * 6 + r) * 1024 + tid];
    }

    // n-gate recurrent biases (r/z biases folded into xp by combine_bias)
    float bn0 = 0.f, bn1 = 0.f;
    if (q == 0) { bn0 = bhh[2 * NH + v]; bn1 = bhh[2 * NH + 128 + v]; }

    __shared__ __align__(16) _Float16 hbuf[NH];
    if (tid < NH) hbuf[tid] = (_Float16)0.f;
    float h0 = 0.f, h1 = 0.f;          // h_old for units v, v+128 (q==0)
    __syncthreads();

    // xp for t=0 (q==0 lanes; xr/xz already include bhh_{r,z})
    const size_t xb = (size_t)b * NT * NG;
    float xr0 = 0.f, xz0 = 0.f, xn0 = 0.f, xr1 = 0.f, xz1 = 0.f, xn1 = 0.f;
    if (q == 0) {
        xr0 = xp[xb + v];            xr1 = xp[xb + 128 + v];
        xz0 = xp[xb + 256 + v];      xz1 = xp[xb + 384 + v];
        xn0 = xp[xb + 512 + v];      xn1 = xp[xb + 640 + v];
    }

    for (int t = 0; t < NT; ++t) {
        // prefetch next step's xp while this step's dot runs
        float pr0 = 0.f, pz0 = 0.f, pn0 = 0.f, pr1 = 0.f, pz1 = 0.f, pn1 = 0.f;
        if (q == 0) {
            const int tn = (t + 1 < NT) ? (t + 1) : t;
            const size_t base = xb + (size_t)tn * NG;
            pr0 = xp[base + v];          pr1 = xp[base + 128 + v];
            pz0 = xp[base + 256 + v];    pz1 = xp[base + 384 + v];
            pn0 = xp[base + 512 + v];    pn1 = xp[base + 640 + v];
        }

        // ---- 6 rows x 32-k dots: 4 ds_read_b128 + 96 fdot2 per thread ----
        const float4* h4 = (const float4*)hbuf;
        float a0 = 0.f, a1 = 0.f, a2 = 0.f, a3 = 0.f, a4 = 0.f, a5 = 0.f;
        #pragma unroll
        for (int i = 0; i < 4; ++i) {
            const int c = (i + q) & 3;           // rotate: 4-way -> 2-way bank
            float4 hb = h4[4 * q + c];
            f16x2 hx = as_f16x2(hb.x);
            f16x2 hy = as_f16x2(hb.y);
            f16x2 hz = as_f16x2(hb.z);
            f16x2 hw = as_f16x2(hb.w);
            #define GRU_ROW(ACC, R)                                  \
                ACC = fdot2(hx, as_f16x2u(w[R][c].x), ACC);          \
                ACC = fdot2(hy, as_f16x2u(w[R][c].y), ACC);          \
                ACC = fdot2(hz, as_f16x2u(w[R][c].z), ACC);          \
                ACC = fdot2(hw, as_f16x2u(w[R][c].w), ACC);
            GRU_ROW(a0, 0) GRU_ROW(a1, 1) GRU_ROW(a2, 2)
            GRU_ROW(a3, 3) GRU_ROW(a4, 4) GRU_ROW(a5, 5)
            #undef GRU_ROW
        }

        // ---- reduce across the 8 k-octant lanes (pure VALU) ----
        a0 = red8(a0); a1 = red8(a1); a2 = red8(a2);
        a3 = red8(a3); a4 = red8(a4); a5 = red8(a5);

        __syncthreads();   // all waves done reading hbuf

        if (q == 0) {
            const float r0 = 1.f / (1.f + __expf(-(xr0 + a0)));
            const float z0 = 1.f / (1.f + __expf(-(xz0 + a1)));
            const float p0 = xn0 + r0 * (a2 + bn0);
            const float e0 = __expf(2.f * p0);
            const float n0 = 1.f - 2.f / (e0 + 1.f);      // tanh(p0)
            h0 = (1.f - z0) * n0 + z0 * h0;

            const float r1 = 1.f / (1.f + __expf(-(xr1 + a3)));
            const float z1 = 1.f / (1.f + __expf(-(xz1 + a4)));
            const float p1 = xn1 + r1 * (a5 + bn1);
            const float e1 = __expf(2.f * p1);
            const float n1 = 1.f - 2.f / (e1 + 1.f);      // tanh(p1)
            h1 = (1.f - z1) * n1 + z1 * h1;

            hbuf[v]       = (_Float16)h0;
            hbuf[128 + v] = (_Float16)h1;
            float* o = out + ((size_t)b * NT + t) * NH;
            o[v]       = h0;
            o[128 + v] = h1;
        }
        __syncthreads();   // new h visible before next step's dots

        xr0 = pr0; xz0 = pz0; xn0 = pn0;
        xr1 = pr1; xz1 = pz1; xn1 = pn1;
    }
}

// ---------------------------------------------------------------------------
// Launch
// ---------------------------------------------------------------------------
extern "C" void kernel_launch(void* const* d_in, const int* in_sizes, int n_in,
                              void* d_out, int out_size, void* d_ws, size_t ws_size,
                              hipStream_t stream)
{
    const float* x      = (const float*)d_in[0];
    const float* ds_w   = (const float*)d_in[1];
    const float* ds_b   = (const float*)d_in[2];
    const float* g1_wih = (const float*)d_in[3];
    const float* g1_whh = (const float*)d_in[4];
    const float* g1_bih = (const float*)d_in[5];
    const float* g1_bhh = (const float*)d_in[6];
    const float* gr_wih = (const float*)d_in[7];
    const float* gr_whh = (const float*)d_in[8];
    const float* gr_bih = (const float*)d_in[9];
    const float* gr_bhh = (const float*)d_in[10];
    const float* gi_wih = (const float*)d_in[11];
    const float* gi_whh = (const float*)d_in[12];
    const float* gi_bih = (const float*)d_in[13];
    const float* gi_bhh = (const float*)d_in[14];
    const float* dr_w   = (const float*)d_in[15];
    const float* dr_b   = (const float*)d_in[16];
    const float* di_w   = (const float*)d_in[17];
    const float* di_b   = (const float*)d_in[18];

    float* out = (float*)d_out;
    float* ws  = (float*)d_ws;

    // workspace layout (float-element offsets)
    unsigned* wpk1 = (unsigned*)ws;
    unsigned* wpkr = wpk1 + WPK_ELEMS;
    unsigned* wpki = wpkr + WPK_ELEMS;
    float* cb1 = ws + 3 * WPK_ELEMS;
    float* cbr = cb1 + CB_ELEMS;
    float* cbi = cbr + CB_ELEMS;
    float* xpA = cbi + CB_ELEMS;

    const size_t need_conc =
        (3 * WPK_ELEMS + 3 * CB_ELEMS + 2 * XP_ELEMS + 3 * H_ELEMS) * sizeof(float);
    const bool conc = ws_size >= need_conc;

    float *xpB, *so, *sg, *r1, *i1;
    if (conc) {
        xpB = xpA + XP_ELEMS;
        so  = xpB + XP_ELEMS;
        sg  = so + H_ELEMS;
        i1  = sg + H_ELEMS;
        r1  = so;            // shared_out consumed before real_1 written
    } else {
        xpB = xpA;           // sequential reuse
        so  = xpA + XP_ELEMS;
        sg  = so + H_ELEMS;
        r1  = so;
        i1  = so;
    }

    const dim3 blk(256);
    const dim3 rblk(1024);
    const dim3 gN256(NM / GEMM_BM, NH / GEMM_BN);                 // 250 x 4
    const dim3 gN768(NM / GEMM_BM, NG / GEMM_BN);                 // 250 x 12
    const dim3 gN513(NM / GEMM_BM, (NF + GEMM_BN - 1) / GEMM_BN); // 250 x 9
    const dim3 gPack((NG * NH / 2) / 4 / 256);                    // 96
    const dim3 gCB(NG / 256);                                     // 3

    // pack recurrent weights to f16 + combine biases (every call)
    pack_whh_f16<<<gPack, blk, 0, stream>>>(g1_whh, wpk1);
    pack_whh_f16<<<gPack, blk, 0, stream>>>(gr_whh, wpkr);
    pack_whh_f16<<<gPack, blk, 0, stream>>>(gi_whh, wpki);
    combine_bias<<<gCB, blk, 0, stream>>>(g1_bih, g1_bhh, cb1);
    combine_bias<<<gCB, blk, 0, stream>>>(gr_bih, gr_bhh, cbr);
    combine_bias<<<gCB, blk, 0, stream>>>(gi_bih, gi_bhh, cbi);

    // shared dense: concat(x) [32000,1026] @ ds_w^T + ds_b -> so [32000,256]
    gemm_bias_kernel<true><<<gN256, blk, 0, stream>>>(x, ds_w, ds_b, so, NM, NH, 2 * NF);
    // xproj for GRU1 (bias = bih + bhh_{r,z})
    gemm_bias_kernel<false><<<gN768, blk, 0, stream>>>(so, g1_wih, cb1, xpA, NM, NG, NH);
    // GRU1 recurrence -> sg
    gru_rec_kernel<<<dim3(NB), rblk, 0, stream>>>(
        xpA, wpk1, g1_bhh, sg, xpA, wpk1, g1_bhh, sg, NB);

    if (conc) {
        gemm_bias_kernel<false><<<gN768, blk, 0, stream>>>(sg, gr_wih, cbr, xpA, NM, NG, NH);
        gemm_bias_kernel<false><<<gN768, blk, 0, stream>>>(sg, gi_wih, cbi, xpB, NM, NG, NH);
        // real + imag recurrences concurrently (64 workgroups)
        gru_rec_kernel<<<dim3(2 * NB), rblk, 0, stream>>>(
            xpA, wpkr, gr_bhh, r1, xpB, wpki, gi_bhh, i1, NB);
        gemm_bias_kernel<false><<<gN513, blk, 0, stream>>>(r1, dr_w, dr_b, out, NM, NF, NH);
        gemm_bias_kernel<false><<<gN513, blk, 0, stream>>>(i1, di_w, di_b, out + OUT_HALF, NM, NF, NH);
    } else {
        gemm_bias_kernel<false><<<gN768, blk, 0, stream>>>(sg, gr_wih, cbr, xpA, NM, NG, NH);
        gru_rec_kernel<<<dim3(NB), rblk, 0, stream>>>(
            xpA, wpkr, gr_bhh, r1, xpA, wpkr, gr_bhh, r1, NB);
        gemm_bias_kernel<false><<<gN513, blk, 0, stream>>>(r1, dr_w, dr_b, out, NM, NF, NH);
        gemm_bias_kernel<false><<<gN768, blk, 0, stream>>>(sg, gi_wih, cbi, xpA, NM, NG, NH);
        gru_rec_kernel<<<dim3(NB), rblk, 0, stream>>>(
            xpA, wpki, gi_bhh, i1, xpA, wpki, gi_bhh, i1, NB);
        gemm_bias_kernel<false><<<gN513, blk, 0, stream>>>(i1, di_w, di_b, out + OUT_HALF, NM, NF, NH);
    }
}

// Round 6
// 8002.477 us; speedup vs baseline: 5.8260x; 5.8260x over previous
//
#include <hip/hip_runtime.h>
#include <cstdint>
#include <cstddef>

// ---------------------------------------------------------------------------
// Problem constants
// ---------------------------------------------------------------------------
#define NB   32          // batch
#define NT   1000        // time steps
#define NF   513         // features
#define NH   256         // hidden
#define NG   768         // 3*NH gate rows
#define NM   (NB*NT)     // 32000 GEMM rows

#define XP_ELEMS  ((size_t)NM * NG)       // 24,576,000
#define H_ELEMS   ((size_t)NM * NH)       //  8,192,000
#define WPK_ELEMS ((size_t)NG * NH / 2)   //  98,304 (f16x2 words)
#define CB_ELEMS  ((size_t)NG)            //  768 combined-bias floats
#define OUT_HALF  ((size_t)NM * NF)       // 16,416,000

typedef _Float16 f16x2 __attribute__((ext_vector_type(2)));

static __device__ __forceinline__ f16x2 as_f16x2(float x) {
    return __builtin_bit_cast(f16x2, x);
}
static __device__ __forceinline__ f16x2 as_f16x2u(unsigned x) {
    return __builtin_bit_cast(f16x2, x);
}

#if __has_builtin(__builtin_amdgcn_fdot2)
static __device__ __forceinline__ float fdot2(f16x2 h, f16x2 w, float acc) {
    return __builtin_amdgcn_fdot2(h, w, acc, false);
}
#else
static __device__ __forceinline__ float fdot2(f16x2 h, f16x2 w, float acc) {
    return acc + (float)h.x * (float)w.x + (float)h.y * (float)w.y;
}
#endif

// In-VALU butterfly reduce across 8 consecutive lanes (no LDS, no barrier).
// Steps: xor1 (quad_perm [1,0,3,2]), xor2 (quad_perm [2,3,0,1]),
// cross-quad via row_half_mirror (valid because after the first two steps
// every lane of a quad holds the quad sum).
template<int CTRL>
static __device__ __forceinline__ float dpp_add(float x) {
    int t = __builtin_amdgcn_update_dpp(0, __builtin_bit_cast(int, x),
                                        CTRL, 0xF, 0xF, true);
    return x + __builtin_bit_cast(float, t);
}
static __device__ __forceinline__ float red8(float x) {
    x = dpp_add<0xB1>(x);    // quad_perm [1,0,3,2]  : xor 1
    x = dpp_add<0x4E>(x);    // quad_perm [2,3,0,1]  : xor 2
    x = dpp_add<0x141>(x);   // row_half_mirror      : cross-quad
    return x;
}

// ---------------------------------------------------------------------------
// Generic tiled fp32 GEMM:  C[M,N] = A[M,K] @ W[N,K]^T + bias[N]
// CONCAT=true: A is x [32][2][1000][513]; row r=(b*1000+t), feature k is
// concat(x[b,0,t,:], x[b,1,t,:]).
// ---------------------------------------------------------------------------
#define GEMM_BM 128
#define GEMM_BN 64
#define GEMM_BK 16

template<bool CONCAT>
__global__ __launch_bounds__(256) void gemm_bias_kernel(
    const float* __restrict__ A, const float* __restrict__ W,
    const float* __restrict__ bias, float* __restrict__ C,
    int M, int N, int K)
{
    __shared__ float As[GEMM_BK][GEMM_BM];   // k-major
    __shared__ float Bs[GEMM_BK][GEMM_BN];
    const int tid = threadIdx.x;
    const int bm = blockIdx.x * GEMM_BM;
    const int bn = blockIdx.y * GEMM_BN;
    const int mt = tid >> 4;      // 0..15
    const int nt = tid & 15;      // 0..15
    const int m0 = mt * 8;
    const int n0 = nt * 4;

    float acc[8][4];
    #pragma unroll
    for (int i = 0; i < 8; ++i)
        #pragma unroll
        for (int j = 0; j < 4; ++j) acc[i][j] = 0.f;

    const bool kvec = ((K & 3) == 0);   // float4 alignment of row starts

    for (int k0 = 0; k0 < K; k0 += GEMM_BK) {
        // ---- stage A tile (128 rows x 16 k) : 512 quads, 2 per thread ----
        #pragma unroll
        for (int i = 0; i < 2; ++i) {
            int qid = tid * 2 + i;
            int m   = qid >> 2;
            int kq  = (qid & 3) << 2;
            int gm  = bm + m;
            int gk  = k0 + kq;
            float v0 = 0.f, v1 = 0.f, v2 = 0.f, v3 = 0.f;
            if (gm < M) {
                if (!CONCAT) {
                    if (kvec && gk + 4 <= K) {
                        float4 v = *(const float4*)(A + (size_t)gm * K + gk);
                        v0 = v.x; v1 = v.y; v2 = v.z; v3 = v.w;
                    } else {
                        if (gk + 0 < K) v0 = A[(size_t)gm * K + gk + 0];
                        if (gk + 1 < K) v1 = A[(size_t)gm * K + gk + 1];
                        if (gk + 2 < K) v2 = A[(size_t)gm * K + gk + 2];
                        if (gk + 3 < K) v3 = A[(size_t)gm * K + gk + 3];
                    }
                } else {
                    int b = gm / NT;
                    int t = gm - b * NT;
                    float tmp[4];
                    #pragma unroll
                    for (int u = 0; u < 4; ++u) {
                        int f = gk + u;
                        float val = 0.f;
                        if (f < K) {
                            int ch = (f >= NF) ? 1 : 0;
                            int ff = f - ch * NF;
                            val = A[(((size_t)(b * 2 + ch)) * NT + t) * NF + ff];
                        }
                        tmp[u] = val;
                    }
                    v0 = tmp[0]; v1 = tmp[1]; v2 = tmp[2]; v3 = tmp[3];
                }
            }
            As[kq + 0][m] = v0; As[kq + 1][m] = v1;
            As[kq + 2][m] = v2; As[kq + 3][m] = v3;
        }
        // ---- stage B tile (64 n-rows x 16 k) : 256 quads, 1 per thread ----
        {
            int n  = tid >> 2;
            int kq = (tid & 3) << 2;
            int gn = bn + n;
            int gk = k0 + kq;
            float v0 = 0.f, v1 = 0.f, v2 = 0.f, v3 = 0.f;
            if (gn < N) {
                if (kvec && gk + 4 <= K) {
                    float4 v = *(const float4*)(W + (size_t)gn * K + gk);
                    v0 = v.x; v1 = v.y; v2 = v.z; v3 = v.w;
                } else {
                    if (gk + 0 < K) v0 = W[(size_t)gn * K + gk + 0];
                    if (gk + 1 < K) v1 = W[(size_t)gn * K + gk + 1];
                    if (gk + 2 < K) v2 = W[(size_t)gn * K + gk + 2];
                    if (gk + 3 < K) v3 = W[(size_t)gn * K + gk + 3];
                }
            }
            Bs[kq + 0][n] = v0; Bs[kq + 1][n] = v1;
            Bs[kq + 2][n] = v2; Bs[kq + 3][n] = v3;
        }
        __syncthreads();
        // ---- micro-kernel ----
        #pragma unroll
        for (int k = 0; k < GEMM_BK; ++k) {
            float a[8], bb[4];
            *(float4*)&a[0] = *(const float4*)&As[k][m0];
            *(float4*)&a[4] = *(const float4*)&As[k][m0 + 4];
            *(float4*)&bb[0] = *(const float4*)&Bs[k][n0];
            #pragma unroll
            for (int i = 0; i < 8; ++i)
                #pragma unroll
                for (int j = 0; j < 4; ++j)
                    acc[i][j] = fmaf(a[i], bb[j], acc[i][j]);
        }
        __syncthreads();
    }
    // ---- epilogue ----
    #pragma unroll
    for (int i = 0; i < 8; ++i) {
        int gm = bm + m0 + i;
        if (gm >= M) continue;
        #pragma unroll
        for (int j = 0; j < 4; ++j) {
            int gn = bn + n0 + j;
            if (gn < N) C[(size_t)gm * N + gn] = acc[i][j] + bias[gn];
        }
    }
}

// ---------------------------------------------------------------------------
// Pack whh [768][256] fp32 -> f16x2 in the EXACT per-thread order the
// recurrence kernel loads:  wq4[(j*6 + r)*1024 + tid]   (uint4 granules)
// where tid = v*8+q, r indexes the thread's 6 rows
//   rows = {v, 256+v, 512+v, 128+v, 384+v, 640+v}
// and the uint4 covers k2 = 16q + 4j .. +3  (k2 = h-pair index).
// Prologue loads become perfectly coalesced (consecutive tid -> consecutive
// 16B), and it is a one-time 393KB read per workgroup.
// ---------------------------------------------------------------------------
__global__ __launch_bounds__(256) void pack_whh_f16(
    const float* __restrict__ whh, unsigned* __restrict__ wpk)
{
    int idx = blockIdx.x * 256 + threadIdx.x;   // 0..24575, one uint4 each
    int t   = idx & 1023;
    int jr  = idx >> 10;          // 0..23
    int j   = jr / 6;
    int r   = jr - j * 6;
    int v   = t >> 3;
    int q   = t & 7;
    int row = (r < 3) ? (r * 256 + v) : ((r - 3) * 256 + 128 + v);
    int k2b = 16 * q + 4 * j;
    unsigned o[4];
    #pragma unroll
    for (int m = 0; m < 4; ++m) {
        f16x2 w;
        w.x = (_Float16)whh[row * NH + 2 * (k2b + m)];
        w.y = (_Float16)whh[row * NH + 2 * (k2b + m) + 1];
        o[m] = __builtin_bit_cast(unsigned, w);
    }
    ((uint4*)wpk)[idx] = make_uint4(o[0], o[1], o[2], o[3]);
}

// cb[g] = bih[g] + bhh[g] for r/z rows (g<512), bih[g] for n rows.
// (bhh_n must stay separate: n = tanh(xn + r*(Whn.h + bhh_n)).)
__global__ __launch_bounds__(256) void combine_bias(
    const float* __restrict__ bih, const float* __restrict__ bhh,
    float* __restrict__ cb)
{
    int g = blockIdx.x * 256 + threadIdx.x;   // 0..767
    cb[g] = bih[g] + (g < 2 * NH ? bhh[g] : 0.f);
}

// ---------------------------------------------------------------------------
// GRU recurrence — 1024 threads, 8-way k-split, 6 rows/thread, DPP reduce.
//
// ROUND-6 FIX (rule #20): round 5's bank-rotation index c=(i+q)&3 was a
// RUNTIME index into w[6][4] -> the whole weight array was allocated in
// scratch (VGPR_Count=56, 23-53ms from spill traffic). All w[][] indices
// are now compile-time (c == i, loops fully unrolled) so the 24 uint4 live
// in VGPRs. The bank rotation is dropped: the resulting 4-way address
// conflict on the broadcast ds_read_b128 is hidden under the 8-cyc/instr
// register-writeback floor (1KB broadcast at 128B/cyc), which itself sits
// under the ~1200cyc VALU cost per step -> conflicts are off the
// critical path.
//
// Thread tid = v*8 + q (v=0..127, q=0..7): owns gate rows
//   {v, 256+v, 512+v} (unit v) and {128+v, 384+v, 640+v} (unit v+128)
// over k in [32q, 32q+32). Partial sums reduced across the 8 q-lanes with
// a 3-step DPP butterfly (pure VALU, no LDS, no barrier); lane q=0 then
// does the gate math for both units. h lives in LDS as f16.
// Two parameter sets so real/imag GRUs run concurrently in one launch.
// ---------------------------------------------------------------------------
__global__ __launch_bounds__(1024) void gru_rec_kernel(
    const float* __restrict__ xpA, const unsigned* __restrict__ wpkA,
    const float* __restrict__ bhhA, float* __restrict__ outA,
    const float* __restrict__ xpB, const unsigned* __restrict__ wpkB,
    const float* __restrict__ bhhB, float* __restrict__ outB,
    int nBatch)
{
    const int wg = blockIdx.x;
    const float* xp;  const unsigned* wpk;  const float* bhh;  float* out;  int b;
    if (wg < nBatch) { xp = xpA; wpk = wpkA; bhh = bhhA; out = outA; b = wg; }
    else             { xp = xpB; wpk = wpkB; bhh = bhhB; out = outB; b = wg - nBatch; }

    const int tid = threadIdx.x;       // 0..1023
    const int v   = tid >> 3;          // 0..127
    const int q   = tid & 7;           // k-octant

    // ---- load this thread's 24 weight quads (coalesced, once) ----
    uint4 w[6][4];
    {
        const uint4* wq4 = (const uint4*)wpk;
        #pragma unroll
        for (int j = 0; j < 4; ++j)
            #pragma unroll
            for (int r = 0; r < 6; ++r)
                w[r][j] = wq4[(size_t)(j * 6 + r) * 1024 + tid];
    }

    // n-gate recurrent biases (r/z biases folded into xp by combine_bias)
    float bn0 = 0.f, bn1 = 0.f;
    if (q == 0) { bn0 = bhh[2 * NH + v]; bn1 = bhh[2 * NH + 128 + v]; }

    __shared__ __align__(16) _Float16 hbuf[NH];
    if (tid < NH) hbuf[tid] = (_Float16)0.f;
    float h0 = 0.f, h1 = 0.f;          // h_old for units v, v+128 (q==0)
    __syncthreads();

    // xp for t=0 (q==0 lanes; xr/xz already include bhh_{r,z})
    const size_t xb = (size_t)b * NT * NG;
    float xr0 = 0.f, xz0 = 0.f, xn0 = 0.f, xr1 = 0.f, xz1 = 0.f, xn1 = 0.f;
    if (q == 0) {
        xr0 = xp[xb + v];            xr1 = xp[xb + 128 + v];
        xz0 = xp[xb + 256 + v];      xz1 = xp[xb + 384 + v];
        xn0 = xp[xb + 512 + v];      xn1 = xp[xb + 640 + v];
    }

    for (int t = 0; t < NT; ++t) {
        // prefetch next step's xp while this step's dot runs
        float pr0 = 0.f, pz0 = 0.f, pn0 = 0.f, pr1 = 0.f, pz1 = 0.f, pn1 = 0.f;
        if (q == 0) {
            const int tn = (t + 1 < NT) ? (t + 1) : t;
            const size_t base = xb + (size_t)tn * NG;
            pr0 = xp[base + v];          pr1 = xp[base + 128 + v];
            pz0 = xp[base + 256 + v];    pz1 = xp[base + 384 + v];
            pn0 = xp[base + 512 + v];    pn1 = xp[base + 640 + v];
        }

        // ---- 6 rows x 32-k dots: 4 ds_read_b128 + 96 fdot2 per thread ----
        // ALL w indices compile-time: i is an unrolled literal (rule #20).
        const float4* h4 = (const float4*)hbuf;
        float a0 = 0.f, a1 = 0.f, a2 = 0.f, a3 = 0.f, a4 = 0.f, a5 = 0.f;
        #pragma unroll
        for (int i = 0; i < 4; ++i) {
            float4 hb = h4[4 * q + i];
            f16x2 hx = as_f16x2(hb.x);
            f16x2 hy = as_f16x2(hb.y);
            f16x2 hz = as_f16x2(hb.z);
            f16x2 hw = as_f16x2(hb.w);
            #define GRU_ROW(ACC, R)                                  \
                ACC = fdot2(hx, as_f16x2u(w[R][i].x), ACC);          \
                ACC = fdot2(hy, as_f16x2u(w[R][i].y), ACC);          \
                ACC = fdot2(hz, as_f16x2u(w[R][i].z), ACC);          \
                ACC = fdot2(hw, as_f16x2u(w[R][i].w), ACC);
            GRU_ROW(a0, 0) GRU_ROW(a1, 1) GRU_ROW(a2, 2)
            GRU_ROW(a3, 3) GRU_ROW(a4, 4) GRU_ROW(a5, 5)
            #undef GRU_ROW
        }

        // ---- reduce across the 8 k-octant lanes (pure VALU) ----
        a0 = red8(a0); a1 = red8(a1); a2 = red8(a2);
        a3 = red8(a3); a4 = red8(a4); a5 = red8(a5);

        __syncthreads();   // all waves done reading hbuf

        if (q == 0) {
            const float r0 = 1.f / (1.f + __expf(-(xr0 + a0)));
            const float z0 = 1.f / (1.f + __expf(-(xz0 + a1)));
            const float p0 = xn0 + r0 * (a2 + bn0);
            const float e0 = __expf(2.f * p0);
            const float n0 = 1.f - 2.f / (e0 + 1.f);      // tanh(p0)
            h0 = (1.f - z0) * n0 + z0 * h0;

            const float r1 = 1.f / (1.f + __expf(-(xr1 + a3)));
            const float z1 = 1.f / (1.f + __expf(-(xz1 + a4)));
            const float p1 = xn1 + r1 * (a5 + bn1);
            const float e1 = __expf(2.f * p1);
            const float n1 = 1.f - 2.f / (e1 + 1.f);      // tanh(p1)
            h1 = (1.f - z1) * n1 + z1 * h1;

            hbuf[v]       = (_Float16)h0;
            hbuf[128 + v] = (_Float16)h1;
            float* o = out + ((size_t)b * NT + t) * NH;
            o[v]       = h0;
            o[128 + v] = h1;
        }
        __syncthreads();   // new h visible before next step's dots

        xr0 = pr0; xz0 = pz0; xn0 = pn0;
        xr1 = pr1; xz1 = pz1; xn1 = pn1;
    }
}

// ---------------------------------------------------------------------------
// Launch
// ---------------------------------------------------------------------------
extern "C" void kernel_launch(void* const* d_in, const int* in_sizes, int n_in,
                              void* d_out, int out_size, void* d_ws, size_t ws_size,
                              hipStream_t stream)
{
    const float* x      = (const float*)d_in[0];
    const float* ds_w   = (const float*)d_in[1];
    const float* ds_b   = (const float*)d_in[2];
    const float* g1_wih = (const float*)d_in[3];
    const float* g1_whh = (const float*)d_in[4];
    const float* g1_bih = (const float*)d_in[5];
    const float* g1_bhh = (const float*)d_in[6];
    const float* gr_wih = (const float*)d_in[7];
    const float* gr_whh = (const float*)d_in[8];
    const float* gr_bih = (const float*)d_in[9];
    const float* gr_bhh = (const float*)d_in[10];
    const float* gi_wih = (const float*)d_in[11];
    const float* gi_whh = (const float*)d_in[12];
    const float* gi_bih = (const float*)d_in[13];
    const float* gi_bhh = (const float*)d_in[14];
    const float* dr_w   = (const float*)d_in[15];
    const float* dr_b   = (const float*)d_in[16];
    const float* di_w   = (const float*)d_in[17];
    const float* di_b   = (const float*)d_in[18];

    float* out = (float*)d_out;
    float* ws  = (float*)d_ws;

    // workspace layout (float-element offsets)
    unsigned* wpk1 = (unsigned*)ws;
    unsigned* wpkr = wpk1 + WPK_ELEMS;
    unsigned* wpki = wpkr + WPK_ELEMS;
    float* cb1 = ws + 3 * WPK_ELEMS;
    float* cbr = cb1 + CB_ELEMS;
    float* cbi = cbr + CB_ELEMS;
    float* xpA = cbi + CB_ELEMS;

    const size_t need_conc =
        (3 * WPK_ELEMS + 3 * CB_ELEMS + 2 * XP_ELEMS + 3 * H_ELEMS) * sizeof(float);
    const bool conc = ws_size >= need_conc;

    float *xpB, *so, *sg, *r1, *i1;
    if (conc) {
        xpB = xpA + XP_ELEMS;
        so  = xpB + XP_ELEMS;
        sg  = so + H_ELEMS;
        i1  = sg + H_ELEMS;
        r1  = so;            // shared_out consumed before real_1 written
    } else {
        xpB = xpA;           // sequential reuse
        so  = xpA + XP_ELEMS;
        sg  = so + H_ELEMS;
        r1  = so;
        i1  = so;
    }

    const dim3 blk(256);
    const dim3 rblk(1024);
    const dim3 gN256(NM / GEMM_BM, NH / GEMM_BN);                 // 250 x 4
    const dim3 gN768(NM / GEMM_BM, NG / GEMM_BN);                 // 250 x 12
    const dim3 gN513(NM / GEMM_BM, (NF + GEMM_BN - 1) / GEMM_BN); // 250 x 9
    const dim3 gPack((NG * NH / 2) / 4 / 256);                    // 96
    const dim3 gCB(NG / 256);                                     // 3

    // pack recurrent weights to f16 + combine biases (every call)
    pack_whh_f16<<<gPack, blk, 0, stream>>>(g1_whh, wpk1);
    pack_whh_f16<<<gPack, blk, 0, stream>>>(gr_whh, wpkr);
    pack_whh_f16<<<gPack, blk, 0, stream>>>(gi_whh, wpki);
    combine_bias<<<gCB, blk, 0, stream>>>(g1_bih, g1_bhh, cb1);
    combine_bias<<<gCB, blk, 0, stream>>>(gr_bih, gr_bhh, cbr);
    combine_bias<<<gCB, blk, 0, stream>>>(gi_bih, gi_bhh, cbi);

    // shared dense: concat(x) [32000,1026] @ ds_w^T + ds_b -> so [32000,256]
    gemm_bias_kernel<true><<<gN256, blk, 0, stream>>>(x, ds_w, ds_b, so, NM, NH, 2 * NF);
    // xproj for GRU1 (bias = bih + bhh_{r,z})
    gemm_bias_kernel<false><<<gN768, blk, 0, stream>>>(so, g1_wih, cb1, xpA, NM, NG, NH);
    // GRU1 recurrence -> sg
    gru_rec_kernel<<<dim3(NB), rblk, 0, stream>>>(
        xpA, wpk1, g1_bhh, sg, xpA, wpk1, g1_bhh, sg, NB);

    if (conc) {
        gemm_bias_kernel<false><<<gN768, blk, 0, stream>>>(sg, gr_wih, cbr, xpA, NM, NG, NH);
        gemm_bias_kernel<false><<<gN768, blk, 0, stream>>>(sg, gi_wih, cbi, xpB, NM, NG, NH);
        // real + imag recurrences concurrently (64 workgroups)
        gru_rec_kernel<<<dim3(2 * NB), rblk, 0, stream>>>(
            xpA, wpkr, gr_bhh, r1, xpB, wpki, gi_bhh, i1, NB);
        gemm_bias_kernel<false><<<gN513, blk, 0, stream>>>(r1, dr_w, dr_b, out, NM, NF, NH);
        gemm_bias_kernel<false><<<gN513, blk, 0, stream>>>(i1, di_w, di_b, out + OUT_HALF, NM, NF, NH);
    } else {
        gemm_bias_kernel<false><<<gN768, blk, 0, stream>>>(sg, gr_wih, cbr, xpA, NM, NG, NH);
        gru_rec_kernel<<<dim3(NB), rblk, 0, stream>>>(
            xpA, wpkr, gr_bhh, r1, xpA, wpkr, gr_bhh, r1, NB);
        gemm_bias_kernel<false><<<gN513, blk, 0, stream>>>(r1, dr_w, dr_b, out, NM, NF, NH);
        gemm_bias_kernel<false><<<gN768, blk, 0, stream>>>(sg, gi_wih, cbi, xpA, NM, NG, NH);
        gru_rec_kernel<<<dim3(NB), rblk, 0, stream>>>(
            xpA, wpki, gi_bhh, i1, xpA, wpki, gi_bhh, i1, NB);
        gemm_bias_kernel<false><<<gN513, blk, 0, stream>>>(i1, di_w, di_b, out + OUT_HALF, NM, NF, NH);
    }
}

// Round 7
// 4995.375 us; speedup vs baseline: 9.3332x; 1.6020x over previous
//
#include <hip/hip_runtime.h>
#include <cstdint>
#include <cstddef>

// ---------------------------------------------------------------------------
// Problem constants
// ---------------------------------------------------------------------------
#define NB   32          // batch
#define NT   1000        // time steps
#define NF   513         // features
#define NH   256         // hidden
#define NG   768         // 3*NH gate rows
#define NM   (NB*NT)     // 32000 GEMM rows

#define XP_ELEMS  ((size_t)NM * NG)       // 24,576,000
#define H_ELEMS   ((size_t)NM * NH)       //  8,192,000
#define WPK_ELEMS ((size_t)NG * NH / 2)   //  98,304 (f16x2 words)
#define CB_ELEMS  ((size_t)NG)            //  768 combined-bias floats
#define OUT_HALF  ((size_t)NM * NF)       // 16,416,000

typedef _Float16 f16x2 __attribute__((ext_vector_type(2)));

static __device__ __forceinline__ f16x2 as_f16x2(float x) {
    return __builtin_bit_cast(f16x2, x);
}
static __device__ __forceinline__ f16x2 as_f16x2u(unsigned x) {
    return __builtin_bit_cast(f16x2, x);
}

#if __has_builtin(__builtin_amdgcn_fdot2)
static __device__ __forceinline__ float fdot2(f16x2 h, f16x2 w, float acc) {
    return __builtin_amdgcn_fdot2(h, w, acc, false);
}
#else
static __device__ __forceinline__ float fdot2(f16x2 h, f16x2 w, float acc) {
    return acc + (float)h.x * (float)w.x + (float)h.y * (float)w.y;
}
#endif

// In-VALU butterfly reduce across 8 consecutive lanes (no LDS, no barrier).
// After quad xor1+xor2 every lane of a quad holds the quad sum; the
// row_half_mirror then adds the neighbouring quad -> every lane of the
// 8-group holds the full 8-lane sum.
template<int CTRL>
static __device__ __forceinline__ float dpp_add(float x) {
    int t = __builtin_amdgcn_update_dpp(0, __builtin_bit_cast(int, x),
                                        CTRL, 0xF, 0xF, true);
    return x + __builtin_bit_cast(float, t);
}
static __device__ __forceinline__ float red8(float x) {
    x = dpp_add<0xB1>(x);    // quad_perm [1,0,3,2]  : xor 1
    x = dpp_add<0x4E>(x);    // quad_perm [2,3,0,1]  : xor 2
    x = dpp_add<0x141>(x);   // row_half_mirror      : cross-quad
    return x;
}

// ---------------------------------------------------------------------------
// Generic tiled fp32 GEMM:  C[M,N] = A[M,K] @ W[N,K]^T + bias[N]
// CONCAT=true: A is x [32][2][1000][513]; row r=(b*1000+t), feature k is
// concat(x[b,0,t,:], x[b,1,t,:]).
// ---------------------------------------------------------------------------
#define GEMM_BM 128
#define GEMM_BN 64
#define GEMM_BK 16

template<bool CONCAT>
__global__ __launch_bounds__(256) void gemm_bias_kernel(
    const float* __restrict__ A, const float* __restrict__ W,
    const float* __restrict__ bias, float* __restrict__ C,
    int M, int N, int K)
{
    __shared__ float As[GEMM_BK][GEMM_BM];   // k-major
    __shared__ float Bs[GEMM_BK][GEMM_BN];
    const int tid = threadIdx.x;
    const int bm = blockIdx.x * GEMM_BM;
    const int bn = blockIdx.y * GEMM_BN;
    const int mt = tid >> 4;      // 0..15
    const int nt = tid & 15;      // 0..15
    const int m0 = mt * 8;
    const int n0 = nt * 4;

    float acc[8][4];
    #pragma unroll
    for (int i = 0; i < 8; ++i)
        #pragma unroll
        for (int j = 0; j < 4; ++j) acc[i][j] = 0.f;

    const bool kvec = ((K & 3) == 0);   // float4 alignment of row starts

    for (int k0 = 0; k0 < K; k0 += GEMM_BK) {
        // ---- stage A tile (128 rows x 16 k) : 512 quads, 2 per thread ----
        #pragma unroll
        for (int i = 0; i < 2; ++i) {
            int qid = tid * 2 + i;
            int m   = qid >> 2;
            int kq  = (qid & 3) << 2;
            int gm  = bm + m;
            int gk  = k0 + kq;
            float v0 = 0.f, v1 = 0.f, v2 = 0.f, v3 = 0.f;
            if (gm < M) {
                if (!CONCAT) {
                    if (kvec && gk + 4 <= K) {
                        float4 v = *(const float4*)(A + (size_t)gm * K + gk);
                        v0 = v.x; v1 = v.y; v2 = v.z; v3 = v.w;
                    } else {
                        if (gk + 0 < K) v0 = A[(size_t)gm * K + gk + 0];
                        if (gk + 1 < K) v1 = A[(size_t)gm * K + gk + 1];
                        if (gk + 2 < K) v2 = A[(size_t)gm * K + gk + 2];
                        if (gk + 3 < K) v3 = A[(size_t)gm * K + gk + 3];
                    }
                } else {
                    int b = gm / NT;
                    int t = gm - b * NT;
                    float tmp[4];
                    #pragma unroll
                    for (int u = 0; u < 4; ++u) {
                        int f = gk + u;
                        float val = 0.f;
                        if (f < K) {
                            int ch = (f >= NF) ? 1 : 0;
                            int ff = f - ch * NF;
                            val = A[(((size_t)(b * 2 + ch)) * NT + t) * NF + ff];
                        }
                        tmp[u] = val;
                    }
                    v0 = tmp[0]; v1 = tmp[1]; v2 = tmp[2]; v3 = tmp[3];
                }
            }
            As[kq + 0][m] = v0; As[kq + 1][m] = v1;
            As[kq + 2][m] = v2; As[kq + 3][m] = v3;
        }
        // ---- stage B tile (64 n-rows x 16 k) : 256 quads, 1 per thread ----
        {
            int n  = tid >> 2;
            int kq = (tid & 3) << 2;
            int gn = bn + n;
            int gk = k0 + kq;
            float v0 = 0.f, v1 = 0.f, v2 = 0.f, v3 = 0.f;
            if (gn < N) {
                if (kvec && gk + 4 <= K) {
                    float4 v = *(const float4*)(W + (size_t)gn * K + gk);
                    v0 = v.x; v1 = v.y; v2 = v.z; v3 = v.w;
                } else {
                    if (gk + 0 < K) v0 = W[(size_t)gn * K + gk + 0];
                    if (gk + 1 < K) v1 = W[(size_t)gn * K + gk + 1];
                    if (gk + 2 < K) v2 = W[(size_t)gn * K + gk + 2];
                    if (gk + 3 < K) v3 = W[(size_t)gn * K + gk + 3];
                }
            }
            Bs[kq + 0][n] = v0; Bs[kq + 1][n] = v1;
            Bs[kq + 2][n] = v2; Bs[kq + 3][n] = v3;
        }
        __syncthreads();
        // ---- micro-kernel ----
        #pragma unroll
        for (int k = 0; k < GEMM_BK; ++k) {
            float a[8], bb[4];
            *(float4*)&a[0] = *(const float4*)&As[k][m0];
            *(float4*)&a[4] = *(const float4*)&As[k][m0 + 4];
            *(float4*)&bb[0] = *(const float4*)&Bs[k][n0];
            #pragma unroll
            for (int i = 0; i < 8; ++i)
                #pragma unroll
                for (int j = 0; j < 4; ++j)
                    acc[i][j] = fmaf(a[i], bb[j], acc[i][j]);
        }
        __syncthreads();
    }
    // ---- epilogue ----
    #pragma unroll
    for (int i = 0; i < 8; ++i) {
        int gm = bm + m0 + i;
        if (gm >= M) continue;
        #pragma unroll
        for (int j = 0; j < 4; ++j) {
            int gn = bn + n0 + j;
            if (gn < N) C[(size_t)gm * N + gn] = acc[i][j] + bias[gn];
        }
    }
}

// ---------------------------------------------------------------------------
// Pack whh [768][256] fp32 -> f16x2 in the EXACT per-thread order the
// recurrence kernel loads:  wq4[(j*6 + r)*1024 + tid]   (uint4 granules)
// where tid = v*8+q, r indexes the thread's 6 rows
//   rows = {v, 256+v, 512+v, 128+v, 384+v, 640+v}
// and the uint4 covers k2 = 16q + 4j .. +3  (k2 = h-pair index).
// Prologue loads become perfectly coalesced (consecutive tid -> consecutive
// 16B), and it is a one-time 393KB read per workgroup.
// ---------------------------------------------------------------------------
__global__ __launch_bounds__(256) void pack_whh_f16(
    const float* __restrict__ whh, unsigned* __restrict__ wpk)
{
    int idx = blockIdx.x * 256 + threadIdx.x;   // 0..24575, one uint4 each
    int t   = idx & 1023;
    int jr  = idx >> 10;          // 0..23
    int j   = jr / 6;
    int r   = jr - j * 6;
    int v   = t >> 3;
    int q   = t & 7;
    int row = (r < 3) ? (r * 256 + v) : ((r - 3) * 256 + 128 + v);
    int k2b = 16 * q + 4 * j;
    unsigned o[4];
    #pragma unroll
    for (int m = 0; m < 4; ++m) {
        f16x2 w;
        w.x = (_Float16)whh[row * NH + 2 * (k2b + m)];
        w.y = (_Float16)whh[row * NH + 2 * (k2b + m) + 1];
        o[m] = __builtin_bit_cast(unsigned, w);
    }
    ((uint4*)wpk)[idx] = make_uint4(o[0], o[1], o[2], o[3]);
}

// cb[g] = bih[g] + bhh[g] for r/z rows (g<512), bih[g] for n rows.
// (bhh_n must stay separate: n = tanh(xn + r*(Whn.h + bhh_n)).)
__global__ __launch_bounds__(256) void combine_bias(
    const float* __restrict__ bih, const float* __restrict__ bhh,
    float* __restrict__ cb)
{
    int g = blockIdx.x * 256 + threadIdx.x;   // 0..767
    cb[g] = bih[g] + (g < 2 * NH ? bhh[g] : 0.f);
}

// ---------------------------------------------------------------------------
// GRU recurrence — 1024 threads, 8-way k-split, 6 rows/thread, DPP reduce.
//
// ROUND-7 FIX (register budget): round 6 kept static w indexing but the
// live set (96 w + 12 xp + 2 bias + 2 h + temps ~ 134) exceeded the HARD
// 128-VGPR cap of a 16-wave workgroup (512 regs/SIMD / 4 waves), so the
// allocator spilled the whole w array (VGPR_Count=64, ~6k cyc/step of
// scratch reloads). red8 leaves the FULL 8-lane sum in EVERY lane, so the
// gate math is now split: lane q=0 of each 8-group handles unit v, lane
// q=4 handles unit v+128. Loop-carried xp regs 12->6, bias 2->1, h 2->1
// (-8 regs, peak ~120 <= 128), and the serial activation section halves
// (two lanes in parallel instead of one lane doing both units).
//
// Thread tid = v*8 + q (v=0..127, q=0..7): owns gate rows
//   {v, 256+v, 512+v} (unit v) and {128+v, 384+v, 640+v} (unit v+128)
// over k in [32q, 32q+32). Partials reduced across the 8 q-lanes with a
// 3-step DPP butterfly (pure VALU, no LDS, no barrier). h lives in LDS
// as f16; dot-loop reads are 8-lane-group broadcasts (4-way bank aliasing
// stays: its ~256 cyc/step on the LDS pipe sits under the ~1200 cyc VALU
// floor, off the critical path).
// Two parameter sets so real/imag GRUs run concurrently in one launch.
// ---------------------------------------------------------------------------
__global__ __launch_bounds__(1024, 4) void gru_rec_kernel(
    const float* __restrict__ xpA, const unsigned* __restrict__ wpkA,
    const float* __restrict__ bhhA, float* __restrict__ outA,
    const float* __restrict__ xpB, const unsigned* __restrict__ wpkB,
    const float* __restrict__ bhhB, float* __restrict__ outB,
    int nBatch)
{
    const int wg = blockIdx.x;
    const float* xp;  const unsigned* wpk;  const float* bhh;  float* out;  int b;
    if (wg < nBatch) { xp = xpA; wpk = wpkA; bhh = bhhA; out = outA; b = wg; }
    else             { xp = xpB; wpk = wpkB; bhh = bhhB; out = outB; b = wg - nBatch; }

    const int tid = threadIdx.x;       // 0..1023
    const int v   = tid >> 3;          // 0..127
    const int q   = tid & 7;           // k-octant

    // role lanes: q==0 -> unit v, q==4 -> unit v+128
    const bool role = ((q & 3) == 0);
    const int  unit = v + ((q >> 2) << 7);

    // ---- load this thread's 24 weight quads (coalesced, once) ----
    uint4 w[6][4];
    {
        const uint4* wq4 = (const uint4*)wpk;
        #pragma unroll
        for (int j = 0; j < 4; ++j)
            #pragma unroll
            for (int r = 0; r < 6; ++r)
                w[r][j] = wq4[(size_t)(j * 6 + r) * 1024 + tid];
    }

    // n-gate recurrent bias for this lane's unit (r/z folded into xp)
    float bn = 0.f;
    if (role) bn = bhh[2 * NH + unit];

    __shared__ __align__(16) _Float16 hbuf[NH];
    if (tid < NH) hbuf[tid] = (_Float16)0.f;
    float h = 0.f;                     // h_old for this lane's unit
    __syncthreads();

    // xp for t=0 (role lanes; xr/xz already include bhh_{r,z})
    const size_t xb = (size_t)b * NT * NG;
    float xr = 0.f, xz = 0.f, xn = 0.f;
    if (role) {
        xr = xp[xb + unit];
        xz = xp[xb + 256 + unit];
        xn = xp[xb + 512 + unit];
    }

    for (int t = 0; t < NT; ++t) {
        // prefetch next step's xp while this step's dot runs
        float pr = 0.f, pz = 0.f, pn = 0.f;
        if (role) {
            const int tn = (t + 1 < NT) ? (t + 1) : t;
            const size_t base = xb + (size_t)tn * NG;
            pr = xp[base + unit];
            pz = xp[base + 256 + unit];
            pn = xp[base + 512 + unit];
        }

        // ---- 6 rows x 32-k dots: 4 ds_read_b128 + 96 fdot2 per thread ----
        // ALL w indices compile-time (rule #20).
        const float4* h4 = (const float4*)hbuf;
        float a0 = 0.f, a1 = 0.f, a2 = 0.f, a3 = 0.f, a4 = 0.f, a5 = 0.f;
        #pragma unroll
        for (int i = 0; i < 4; ++i) {
            float4 hb = h4[4 * q + i];
            f16x2 hx = as_f16x2(hb.x);
            f16x2 hy = as_f16x2(hb.y);
            f16x2 hz = as_f16x2(hb.z);
            f16x2 hw = as_f16x2(hb.w);
            #define GRU_ROW(ACC, R)                                  \
                ACC = fdot2(hx, as_f16x2u(w[R][i].x), ACC);          \
                ACC = fdot2(hy, as_f16x2u(w[R][i].y), ACC);          \
                ACC = fdot2(hz, as_f16x2u(w[R][i].z), ACC);          \
                ACC = fdot2(hw, as_f16x2u(w[R][i].w), ACC);
            GRU_ROW(a0, 0) GRU_ROW(a1, 1) GRU_ROW(a2, 2)
            GRU_ROW(a3, 3) GRU_ROW(a4, 4) GRU_ROW(a5, 5)
            #undef GRU_ROW
        }

        // ---- reduce across the 8 k-octant lanes (pure VALU) ----
        // Full sum lands in EVERY lane of the 8-group.
        a0 = red8(a0); a1 = red8(a1); a2 = red8(a2);
        a3 = red8(a3); a4 = red8(a4); a5 = red8(a5);

        __syncthreads();   // all waves done reading hbuf

        if (role) {
            const bool hi = (q & 4) != 0;
            const float sr = hi ? a3 : a0;
            const float sz = hi ? a4 : a1;
            const float sn = hi ? a5 : a2;
            const float r    = 1.f / (1.f + __expf(-(xr + sr)));
            const float z    = 1.f / (1.f + __expf(-(xz + sz)));
            const float p    = xn + r * (sn + bn);
            const float e2   = __expf(2.f * p);
            const float n    = 1.f - 2.f / (e2 + 1.f);      // tanh(p)
            h = (1.f - z) * n + z * h;
            hbuf[unit] = (_Float16)h;
            out[((size_t)b * NT + t) * NH + unit] = h;
        }
        __syncthreads();   // new h visible before next step's dots

        xr = pr; xz = pz; xn = pn;
    }
}

// ---------------------------------------------------------------------------
// Launch
// ---------------------------------------------------------------------------
extern "C" void kernel_launch(void* const* d_in, const int* in_sizes, int n_in,
                              void* d_out, int out_size, void* d_ws, size_t ws_size,
                              hipStream_t stream)
{
    const float* x      = (const float*)d_in[0];
    const float* ds_w   = (const float*)d_in[1];
    const float* ds_b   = (const float*)d_in[2];
    const float* g1_wih = (const float*)d_in[3];
    const float* g1_whh = (const float*)d_in[4];
    const float* g1_bih = (const float*)d_in[5];
    const float* g1_bhh = (const float*)d_in[6];
    const float* gr_wih = (const float*)d_in[7];
    const float* gr_whh = (const float*)d_in[8];
    const float* gr_bih = (const float*)d_in[9];
    const float* gr_bhh = (const float*)d_in[10];
    const float* gi_wih = (const float*)d_in[11];
    const float* gi_whh = (const float*)d_in[12];
    const float* gi_bih = (const float*)d_in[13];
    const float* gi_bhh = (const float*)d_in[14];
    const float* dr_w   = (const float*)d_in[15];
    const float* dr_b   = (const float*)d_in[16];
    const float* di_w   = (const float*)d_in[17];
    const float* di_b   = (const float*)d_in[18];

    float* out = (float*)d_out;
    float* ws  = (float*)d_ws;

    // workspace layout (float-element offsets)
    unsigned* wpk1 = (unsigned*)ws;
    unsigned* wpkr = wpk1 + WPK_ELEMS;
    unsigned* wpki = wpkr + WPK_ELEMS;
    float* cb1 = ws + 3 * WPK_ELEMS;
    float* cbr = cb1 + CB_ELEMS;
    float* cbi = cbr + CB_ELEMS;
    float* xpA = cbi + CB_ELEMS;

    const size_t need_conc =
        (3 * WPK_ELEMS + 3 * CB_ELEMS + 2 * XP_ELEMS + 3 * H_ELEMS) * sizeof(float);
    const bool conc = ws_size >= need_conc;

    float *xpB, *so, *sg, *r1, *i1;
    if (conc) {
        xpB = xpA + XP_ELEMS;
        so  = xpB + XP_ELEMS;
        sg  = so + H_ELEMS;
        i1  = sg + H_ELEMS;
        r1  = so;            // shared_out consumed before real_1 written
    } else {
        xpB = xpA;           // sequential reuse
        so  = xpA + XP_ELEMS;
        sg  = so + H_ELEMS;
        r1  = so;
        i1  = so;
    }

    const dim3 blk(256);
    const dim3 rblk(1024);
    const dim3 gN256(NM / GEMM_BM, NH / GEMM_BN);                 // 250 x 4
    const dim3 gN768(NM / GEMM_BM, NG / GEMM_BN);                 // 250 x 12
    const dim3 gN513(NM / GEMM_BM, (NF + GEMM_BN - 1) / GEMM_BN); // 250 x 9
    const dim3 gPack((NG * NH / 2) / 4 / 256);                    // 96
    const dim3 gCB(NG / 256);                                     // 3

    // pack recurrent weights to f16 + combine biases (every call)
    pack_whh_f16<<<gPack, blk, 0, stream>>>(g1_whh, wpk1);
    pack_whh_f16<<<gPack, blk, 0, stream>>>(gr_whh, wpkr);
    pack_whh_f16<<<gPack, blk, 0, stream>>>(gi_whh, wpki);
    combine_bias<<<gCB, blk, 0, stream>>>(g1_bih, g1_bhh, cb1);
    combine_bias<<<gCB, blk, 0, stream>>>(gr_bih, gr_bhh, cbr);
    combine_bias<<<gCB, blk, 0, stream>>>(gi_bih, gi_bhh, cbi);

    // shared dense: concat(x) [32000,1026] @ ds_w^T + ds_b -> so [32000,256]
    gemm_bias_kernel<true><<<gN256, blk, 0, stream>>>(x, ds_w, ds_b, so, NM, NH, 2 * NF);
    // xproj for GRU1 (bias = bih + bhh_{r,z})
    gemm_bias_kernel<false><<<gN768, blk, 0, stream>>>(so, g1_wih, cb1, xpA, NM, NG, NH);
    // GRU1 recurrence -> sg
    gru_rec_kernel<<<dim3(NB), rblk, 0, stream>>>(
        xpA, wpk1, g1_bhh, sg, xpA, wpk1, g1_bhh, sg, NB);

    if (conc) {
        gemm_bias_kernel<false><<<gN768, blk, 0, stream>>>(sg, gr_wih, cbr, xpA, NM, NG, NH);
        gemm_bias_kernel<false><<<gN768, blk, 0, stream>>>(sg, gi_wih, cbi, xpB, NM, NG, NH);
        // real + imag recurrences concurrently (64 workgroups)
        gru_rec_kernel<<<dim3(2 * NB), rblk, 0, stream>>>(
            xpA, wpkr, gr_bhh, r1, xpB, wpki, gi_bhh, i1, NB);
        gemm_bias_kernel<false><<<gN513, blk, 0, stream>>>(r1, dr_w, dr_b, out, NM, NF, NH);
        gemm_bias_kernel<false><<<gN513, blk, 0, stream>>>(i1, di_w, di_b, out + OUT_HALF, NM, NF, NH);
    } else {
        gemm_bias_kernel<false><<<gN768, blk, 0, stream>>>(sg, gr_wih, cbr, xpA, NM, NG, NH);
        gru_rec_kernel<<<dim3(NB), rblk, 0, stream>>>(
            xpA, wpkr, gr_bhh, r1, xpA, wpkr, gr_bhh, r1, NB);
        gemm_bias_kernel<false><<<gN513, blk, 0, stream>>>(r1, dr_w, dr_b, out, NM, NF, NH);
        gemm_bias_kernel<false><<<gN768, blk, 0, stream>>>(sg, gi_wih, cbi, xpA, NM, NG, NH);
        gru_rec_kernel<<<dim3(NB), rblk, 0, stream>>>(
            xpA, wpki, gi_bhh, i1, xpA, wpki, gi_bhh, i1, NB);
        gemm_bias_kernel<false><<<gN513, blk, 0, stream>>>(i1, di_w, di_b, out + OUT_HALF, NM, NF, NH);
    }
}